// Round 9
// baseline (2986.546 us; speedup 1.0000x reference)
//
#include <hip/hip_runtime.h>

// ResidualVectorQuantizer: N=131072, DIM=128, LEVELS=3, K=1024, BETA=0.25, USAGE_REG=1e-3
// Outputs (flat fp32 in d_out): quantized [N*128] | codes [N*3] | commit | usage
//
// Numerics contract with the np fp32 reference (validated previously — do not change):
//  - m = x·W_k: strict sequential fmaf chain over k=0..127, single accumulator.
//  - d = (S - 2*m) + w via __fsub_rn/__fmul_rn/__fadd_rn (no contraction).
//  - argmin: first occurrence on ties == lexicographic (value,index) min
//    (value-min butterfly + exact-equality first-index — validated r13).
//  - residual chain (x - q0) - q1 elementwise fp32, recomputed from codes per
//    level; Srow per-8-elem square sums + 16-chunk ascending sum (stage_level,
//    validated r11/r6 run). Losses loose (~2%); __expf on probs path (r13 ok).
//
// Round 14. r7/r8 post-mortem: the LDS-tiled structure is LDS-PIPE-bound, not
// FMA-bound. LDS is 1 pipe/CU for 4 SIMDs; per kt each wave did 12 LDS ops
// (8 tiny 16B row BROADCASTS + wv + staging) ~ 85-100 LDS cyc vs 64 FMA
// cyc/SIMD-share -> CU LDS demand 1.3-2.2x FMA demand at 12-24 waves. The 7.9M
// bank conflicts were phase-0's rowT writes (16 lanes same r -> 16-way), not wv.
// Fix: rows are WAVE-UNIFORM -> move them to the scalar pipe (s_load_dwordx16,
// r6 proved scalarization: SGPR=96), keep W in the r7-proven LDS double-buffer
// (one vmcnt region/tile; LDS-bounded occupancy disarms the register war).
// Per kt: LDS = 4 wv reads + 4 staging writes per 512 FMA cyc -> FMA-bound.
// stage_level (r6, validated) materializes resT[k][n] in the quantized region
// (only written by the final gather) + SrowG. LDS ~34KB -> 4 blocks/CU ->
// compiler occupancy target 4 waves/EU -> VGPR budget 128 for ~90 live.
// Checks: VGPR 85-115 (64 = war lost), rvq bank-conflicts <0.5M, VALUBusy
// 60-80%, rvq dur 300-480/level.

#define NROWS   131072
#define DIMS    128
#define KCODES  1024
#define NLEV    3

#define QF_OFF   ((size_t)NROWS * DIMS)          // 16777216
#define CODE_OFF QF_OFF
#define SCAL_OFF (QF_OFF + (size_t)NROWS * 3)    // 17170432

// ---------------- ws layout ----------------
// avgp   : 3*1024 floats  @ 0        (12288 B)
// commit : 3 doubles      @ 12288    (24 B)
// wk     : 3*1024 floats  @ 12320    (12288 B)
// WT     : 3*128*1024 fl  @ 24608    (1572864 B)  k-major codebooks WT[l][k][c]
// SrowG  : 131072 floats  @ 1597472  (524288 B)   per-level ||residual row||^2
#define WS_COMMIT_OFF 12288
#define WS_WK_OFF     12320
#define WS_WT_OFF     24608
#define WS_SROW_OFF   1597472

__global__ __launch_bounds__(256) void init_acc(float* avgp, double* commit) {
    for (int i = threadIdx.x; i < 3072; i += 256) avgp[i] = 0.0f;
    if (threadIdx.x < 3) commit[threadIdx.x] = 0.0;
}

__global__ __launch_bounds__(256) void wnorm_kernel(const float* __restrict__ W,
                                                    float* __restrict__ wk) {
    const int wave = threadIdx.x >> 6, lane = threadIdx.x & 63;
    const int c = blockIdx.x * 4 + wave;          // 0..3071 (level*1024 + k)
    const float2 v = *(const float2*)(W + (size_t)c * DIMS + 2 * lane);
    float s = v.x * v.x + v.y * v.y;
#pragma unroll
    for (int m = 32; m >= 1; m >>= 1) s += __shfl_xor(s, m, 64);
    if (lane == 0) wk[c] = s;
}

// WT[l][k][c] = W[l][c][k]   (plain k-major)
__global__ __launch_bounds__(256) void transpose_w(const float* __restrict__ W,
                                                   float* __restrict__ WT) {
    __shared__ float tile[32][65];
    const int l = blockIdx.z, k0 = blockIdx.y * 32, c0 = blockIdx.x * 64;
    const float* Wl = W + (size_t)l * KCODES * DIMS;
    float* WTl = WT + (size_t)l * DIMS * KCODES;
    {
        const int ci = threadIdx.x >> 2;            // 0..63
        const int kg = (threadIdx.x & 3) * 8;       // 0,8,16,24
        const float4 a = *(const float4*)(Wl + (size_t)(c0 + ci) * DIMS + k0 + kg);
        const float4 b = *(const float4*)(Wl + (size_t)(c0 + ci) * DIMS + k0 + kg + 4);
        tile[kg + 0][ci] = a.x; tile[kg + 1][ci] = a.y;
        tile[kg + 2][ci] = a.z; tile[kg + 3][ci] = a.w;
        tile[kg + 4][ci] = b.x; tile[kg + 5][ci] = b.y;
        tile[kg + 6][ci] = b.z; tile[kg + 7][ci] = b.w;
    }
    __syncthreads();
    {
        const int k = threadIdx.x >> 3;             // 0..31
        const int cg = (threadIdx.x & 7) * 8;       // 0..56
        float4 o0, o1;
        o0.x = tile[k][cg + 0]; o0.y = tile[k][cg + 1];
        o0.z = tile[k][cg + 2]; o0.w = tile[k][cg + 3];
        o1.x = tile[k][cg + 4]; o1.y = tile[k][cg + 5];
        o1.z = tile[k][cg + 6]; o1.w = tile[k][cg + 7];
        *(float4*)(WTl + (size_t)(k0 + k) * KCODES + c0 + cg)     = o0;
        *(float4*)(WTl + (size_t)(k0 + k) * KCODES + c0 + cg + 4) = o1;
    }
}

// stage_level: residual rows for `level`, written k-major (resT[k][n]) + Srow.
// Residual chain and Srow chunk sums are bit-identical to the in-kernel phase 0
// (same __fsub_rn order per element, same 8-elem square chains, same 16-chunk
// ascending Srow sum) — validated in the round-11 run.
__global__ __launch_bounds__(256) void stage_level(
    const float* __restrict__ x, const float* __restrict__ W,
    const float* __restrict__ codesF, float* __restrict__ resT,
    float* __restrict__ SrowG, const int level) {

    __shared__ float tileT[128][68];   // [k][r], padded
    __shared__ float redf[64][17];
    const int t = threadIdx.x;
    const int r = t >> 2, iq = t & 3;               // 64 rows x 4 quarters
    const size_t n = (size_t)blockIdx.x * 64 + r;

    float4 v[8];
#pragma unroll
    for (int j = 0; j < 8; ++j)
        v[j] = *(const float4*)(x + n * DIMS + iq * 32 + j * 4);
    for (int l = 0; l < level; ++l) {
        const int idx = (int)codesF[n * 3 + l];
        const float* q = W + ((size_t)(l * KCODES + idx)) * DIMS + iq * 32;
#pragma unroll
        for (int j = 0; j < 8; ++j) {
            const float4 qv = *(const float4*)(q + j * 4);
            v[j].x = __fsub_rn(v[j].x, qv.x);
            v[j].y = __fsub_rn(v[j].y, qv.y);
            v[j].z = __fsub_rn(v[j].z, qv.z);
            v[j].w = __fsub_rn(v[j].w, qv.w);
        }
    }
#pragma unroll
    for (int j = 0; j < 8; ++j) {
        const int k = iq * 32 + j * 4;
        tileT[k + 0][r] = v[j].x; tileT[k + 1][r] = v[j].y;
        tileT[k + 2][r] = v[j].z; tileT[k + 3][r] = v[j].w;
    }
#pragma unroll
    for (int jj = 0; jj < 4; ++jj) {    // chunk index = iq*4+jj, elems *8..*8+7
        const float4 a = v[2 * jj], b = v[2 * jj + 1];
        float sq = a.x * a.x + a.y * a.y + a.z * a.z + a.w * a.w
                 + b.x * b.x + b.y * b.y + b.z * b.z + b.w * b.w;
        redf[r][iq * 4 + jj] = sq;
    }
    __syncthreads();
    if (t < 64) {
        float s = 0.f;
        for (int i = 0; i < 16; ++i) s += redf[t][i];
        SrowG[(size_t)blockIdx.x * 64 + t] = s;
    }
    {
        const int k = t >> 1, half = t & 1;         // 128 k-rows x 2 halves
        float* dst = resT + (size_t)k * NROWS + (size_t)blockIdx.x * 64 + half * 32;
#pragma unroll
        for (int j = 0; j < 8; ++j)
            *(float4*)(dst + 4 * j) = *(const float4*)&tileT[k][half * 32 + 4 * j];
    }
}

// In-place FMA on the accumulator; rs is wave-uniform (SGPR operand of v_fmac).
// Same fmaf chain order (k ascending, single accumulator) as all prior rounds.
#define FMA4(A, rs, wv)                                                        \
    A.x = fmaf(rs, wv.x, A.x); A.y = fmaf(rs, wv.y, A.y);                      \
    A.z = fmaf(rs, wv.z, A.z); A.w = fmaf(rs, wv.w, A.w);

__global__ __launch_bounds__(256) void rvq_level(
    const float* __restrict__ resT, const float* __restrict__ SrowG,
    const float* __restrict__ WT, const float* __restrict__ wk,
    float* __restrict__ out, float* __restrict__ avgp,
    double* __restrict__ commit, const int level) {

    __shared__ float Wtile[2][4096];   // double-buffered W tile: 4 k-rows x 1024
    __shared__ float wminv[16][4];     // per-wave argmin partials
    __shared__ int   wmini[16][4];
    __shared__ float rowmin[16];
    __shared__ float wsum[16][4];
    __shared__ float rcpL[16];

    const int t = threadIdx.x;
    const int wave = t >> 6, lane = t & 63;
    const int c = wave * 256 + lane * 4;          // this thread's 4 codes
    const size_t base = (size_t)blockIdx.x * 16;
    const float* WTl = WT + (size_t)level * DIMS * KCODES;
    const float* wkl = wk + level * KCODES;

    float4 acc[16];
#pragma unroll
    for (int r = 0; r < 16; ++r) { acc[r].x = 0.f; acc[r].y = 0.f; acc[r].z = 0.f; acc[r].w = 0.f; }

    // prologue: stage tile 0 (k-rows 0..3) into buf 0 via registers
    {
        const float4 h0 = *(const float4*)(WTl + 0 * 1024 + t * 4);
        const float4 h1 = *(const float4*)(WTl + 1 * 1024 + t * 4);
        const float4 h2 = *(const float4*)(WTl + 2 * 1024 + t * 4);
        const float4 h3 = *(const float4*)(WTl + 3 * 1024 + t * 4);
        *(float4*)&Wtile[0][0 * 1024 + t * 4] = h0;
        *(float4*)&Wtile[0][1 * 1024 + t * 4] = h1;
        *(float4*)&Wtile[0][2 * 1024 + t * 4] = h2;
        *(float4*)&Wtile[0][3 * 1024 + t * 4] = h3;
    }
    __syncthreads();

    int buf = 0;
#pragma unroll 1
    for (int kt = 0; kt < 32; ++kt) {
        // issue-early: global loads for tile kt+1 (clamped; dead on last iter)
        const float* Wn = WTl + (size_t)((kt + 1 < 32) ? (kt + 1) : 0) * 4096;
        const float4 g0 = *(const float4*)(Wn + 0 * 1024 + t * 4);
        const float4 g1 = *(const float4*)(Wn + 1 * 1024 + t * 4);
        const float4 g2 = *(const float4*)(Wn + 2 * 1024 + t * 4);
        const float4 g3 = *(const float4*)(Wn + 3 * 1024 + t * 4);

        // rows k = 4kt..4kt+3, 16 rows each: wave-uniform -> scalar loads
        const float* rb = resT + (size_t)(kt * 4) * NROWS + base;
        const float* Wt = &Wtile[buf][0];
        {
            float rk[16];
#pragma unroll
            for (int i = 0; i < 16; ++i) rk[i] = rb[i];
            const float4 wv = *(const float4*)&Wt[0 * 1024 + c];
#pragma unroll
            for (int r = 0; r < 16; ++r) { FMA4(acc[r], rk[r], wv); }
        }
        {
            float rk[16];
#pragma unroll
            for (int i = 0; i < 16; ++i) rk[i] = rb[NROWS + i];
            const float4 wv = *(const float4*)&Wt[1 * 1024 + c];
#pragma unroll
            for (int r = 0; r < 16; ++r) { FMA4(acc[r], rk[r], wv); }
        }
        {
            float rk[16];
#pragma unroll
            for (int i = 0; i < 16; ++i) rk[i] = rb[2 * NROWS + i];
            const float4 wv = *(const float4*)&Wt[2 * 1024 + c];
#pragma unroll
            for (int r = 0; r < 16; ++r) { FMA4(acc[r], rk[r], wv); }
        }
        {
            float rk[16];
#pragma unroll
            for (int i = 0; i < 16; ++i) rk[i] = rb[3 * NROWS + i];
            const float4 wv = *(const float4*)&Wt[3 * 1024 + c];
#pragma unroll
            for (int r = 0; r < 16; ++r) { FMA4(acc[r], rk[r], wv); }
        }

        // write-late: vmcnt wait lands here, AFTER the ~1024-cycle FMA block
        *(float4*)&Wtile[buf ^ 1][0 * 1024 + t * 4] = g0;
        *(float4*)&Wtile[buf ^ 1][1 * 1024 + t * 4] = g1;
        *(float4*)&Wtile[buf ^ 1][2 * 1024 + t * 4] = g2;
        *(float4*)&Wtile[buf ^ 1][3 * 1024 + t * 4] = g3;
        __syncthreads();
        buf ^= 1;
    }

    // ---- phase 2: d in place; per-row argmin (value butterfly + equality
    // first-index, bit-identical to lexicographic — validated r13). ----
    const float4 wkv = *(const float4*)(wkl + c);
#pragma unroll
    for (int r = 0; r < 16; ++r) {
        const float Sr = SrowG[base + r];           // wave-uniform scalar load
        float4 A = acc[r];
        A.x = __fadd_rn(__fsub_rn(Sr, __fmul_rn(2.0f, A.x)), wkv.x);
        A.y = __fadd_rn(__fsub_rn(Sr, __fmul_rn(2.0f, A.y)), wkv.y);
        A.z = __fadd_rn(__fsub_rn(Sr, __fmul_rn(2.0f, A.z)), wkv.z);
        A.w = __fadd_rn(__fsub_rn(Sr, __fmul_rn(2.0f, A.w)), wkv.w);
        acc[r] = A;
        float v = fminf(fminf(A.x, A.y), fminf(A.z, A.w));
#pragma unroll
        for (int m = 1; m < 64; m <<= 1) v = fminf(v, __shfl_xor(v, m, 64));
        int bi = 0x7FFFFFFF;                       // first index with d == vmin
        if (A.w == v) bi = c + 3;
        if (A.z == v) bi = c + 2;
        if (A.y == v) bi = c + 1;
        if (A.x == v) bi = c;
#pragma unroll
        for (int m = 1; m < 64; m <<= 1) bi = min(bi, __shfl_xor(bi, m, 64));
        if (lane == 0) { wminv[r][wave] = v; wmini[r][wave] = bi; }
    }
    __syncthreads();
    if (t < 16) {
        float v = wminv[t][0];
        for (int w = 1; w < 4; ++w) v = fminf(v, wminv[t][w]);
        int bi = 0x7FFFFFFF;
        for (int w = 3; w >= 0; --w)
            if (wminv[t][w] == v) bi = (wmini[t][w] < bi) ? wmini[t][w] : bi;
        rowmin[t] = v;
        out[CODE_OFF + (base + t) * 3 + level] = (float)bi;
    }
    __syncthreads();

    // ---- phase 3: e = exp(dmin - d) in place (__expf: probs-only path),
    // row sums via shuffle ----
#pragma unroll
    for (int r = 0; r < 16; ++r) {
        const float mn = rowmin[r];
        float4 A = acc[r];
        A.x = __expf(__fsub_rn(mn, A.x));
        A.y = __expf(__fsub_rn(mn, A.y));
        A.z = __expf(__fsub_rn(mn, A.z));
        A.w = __expf(__fsub_rn(mn, A.w));
        acc[r] = A;
        float s = (A.x + A.y) + (A.z + A.w);
#pragma unroll
        for (int m = 1; m < 64; m <<= 1) s += __shfl_xor(s, m, 64);
        if (lane == 0) wsum[r][wave] = s;
    }
    __syncthreads();
    if (t < 16) {
        const float L = (wsum[t][0] + wsum[t][1]) + (wsum[t][2] + wsum[t][3]);
        rcpL[t] = 1.0f / L;
    }
    if (t == 64) {   // commit partial: d at argmin == ||r - q||^2 (loss tolerance loose)
        double cs = 0.0;
        for (int r = 0; r < 16; ++r) cs += (double)rowmin[r];
        atomicAdd(&commit[level], cs);
    }
    __syncthreads();

    // ---- phase 4: avg_probs partials (fp32 atomics, one per code per block) ----
    {
        float s0 = 0.f, s1 = 0.f, s2 = 0.f, s3 = 0.f;
#pragma unroll
        for (int r = 0; r < 16; ++r) {
            const float rl = rcpL[r];
            s0 = fmaf(acc[r].x, rl, s0);
            s1 = fmaf(acc[r].y, rl, s1);
            s2 = fmaf(acc[r].z, rl, s2);
            s3 = fmaf(acc[r].w, rl, s3);
        }
        atomicAdd(&avgp[level * KCODES + c + 0], s0);
        atomicAdd(&avgp[level * KCODES + c + 1], s1);
        atomicAdd(&avgp[level * KCODES + c + 2], s2);
        atomicAdd(&avgp[level * KCODES + c + 3], s3);
    }
}

__global__ __launch_bounds__(256) void finalize_kernel(const float* __restrict__ avgp,
                                                       const double* __restrict__ commit,
                                                       float* __restrict__ out) {
    __shared__ double red[256];
    __shared__ float  kls[3];
    const int t = threadIdx.x;
    for (int l = 0; l < 3; ++l) {
        double p = 0.0;
        for (int k = t; k < KCODES; k += 256) {
            const float avg = avgp[l * KCODES + k] * (1.0f / 131072.0f);
            p += (double)avg * log((double)avg * 1024.0 + 1e-8);
        }
        red[t] = p; __syncthreads();
        for (int off = 128; off >= 1; off >>= 1) {
            if (t < off) red[t] += red[t + off];
            __syncthreads();
        }
        if (t == 0) kls[l] = (float)red[0];
        __syncthreads();
    }
    if (t == 0) {
        float cv = 0.f, u = 0.f;
        for (int l = 0; l < 3; ++l) {
            const float m = (float)(commit[l] * (1.0 / 16777216.0));
            cv = __fadd_rn(cv, m);                      // + mean((sg(r)-q)^2)
            cv = __fadd_rn(cv, __fmul_rn(0.25f, m));    // + BETA * mean((r-sg(q))^2)
            u = __fadd_rn(u, __fmul_rn(1e-3f, kls[l]));
        }
        out[SCAL_OFF]     = cv;
        out[SCAL_OFF + 1] = u;
    }
}

__global__ __launch_bounds__(256) void gather_kernel(const float* __restrict__ W,
                                                     float* __restrict__ out) {
    const size_t g = (size_t)blockIdx.x * 256 + threadIdx.x;   // f4 index
    const size_t n = g >> 5;
    const int f = (int)(g & 31);
    const float* codes = out + CODE_OFF + n * 3;
    const int c0 = (int)codes[0], c1 = (int)codes[1], c2 = (int)codes[2];
    const float4 a = *(const float4*)(W + (size_t)c0 * DIMS + 4 * f);
    const float4 b = *(const float4*)(W + (size_t)(KCODES + c1) * DIMS + 4 * f);
    const float4 c = *(const float4*)(W + (size_t)(2 * KCODES + c2) * DIMS + 4 * f);
    float4 o;   // ((q1 + q2) + q3), fp32 like reference
    o.x = __fadd_rn(__fadd_rn(a.x, b.x), c.x);
    o.y = __fadd_rn(__fadd_rn(a.y, b.y), c.y);
    o.z = __fadd_rn(__fadd_rn(a.z, b.z), c.z);
    o.w = __fadd_rn(__fadd_rn(a.w, b.w), c.w);
    *(float4*)(out + n * DIMS + 4 * f) = o;
}

extern "C" void kernel_launch(void* const* d_in, const int* in_sizes, int n_in,
                              void* d_out, int out_size, void* d_ws, size_t ws_size,
                              hipStream_t stream) {
    const float* x = (const float*)d_in[0];
    const float* W = (const float*)d_in[1];
    float* out = (float*)d_out;
    float*  avgp   = (float*)d_ws;
    double* commit = (double*)((char*)d_ws + WS_COMMIT_OFF);
    float*  wkp    = (float*)((char*)d_ws + WS_WK_OFF);
    float*  WT     = (float*)((char*)d_ws + WS_WT_OFF);
    float*  SrowG  = (float*)((char*)d_ws + WS_SROW_OFF);
    float*  resT   = out;                          // scratch: quantized region,
                                                   // overwritten last by gather
    const float* codesF = out + CODE_OFF;

    hipLaunchKernelGGL(init_acc, dim3(1), dim3(256), 0, stream, avgp, commit);
    hipLaunchKernelGGL(wnorm_kernel, dim3(768), dim3(256), 0, stream, W, wkp);
    hipLaunchKernelGGL(transpose_w, dim3(16, 4, 3), dim3(256), 0, stream, W, WT);
    for (int l = 0; l < NLEV; ++l) {
        hipLaunchKernelGGL(stage_level, dim3(NROWS / 64), dim3(256), 0, stream,
                           x, W, codesF, resT, SrowG, l);
        hipLaunchKernelGGL(rvq_level, dim3(NROWS / 16), dim3(256), 0, stream,
                           resT, SrowG, WT, wkp, out, avgp, commit, l);
    }
    hipLaunchKernelGGL(finalize_kernel, dim3(1), dim3(256), 0, stream, avgp, commit, out);
    hipLaunchKernelGGL(gather_kernel, dim3((NROWS * 32) / 256), dim3(256), 0, stream, W, out);
}

// Round 10
// 2208.808 us; speedup vs baseline: 1.3521x; 1.3521x over previous
//
#include <hip/hip_runtime.h>

// ResidualVectorQuantizer: N=131072, DIM=128, LEVELS=3, K=1024, BETA=0.25, USAGE_REG=1e-3
// Outputs (flat fp32 in d_out): quantized [N*128] | codes [N*3] | commit | usage
//
// Numerics contract with the np fp32 reference (validated previously — do not change):
//  - m = x·W_k: strict sequential fmaf chain over k=0..127, single accumulator.
//  - d = (S - 2*m) + w via __fsub_rn/__fmul_rn/__fadd_rn (no contraction).
//  - argmin: first occurrence on ties == lexicographic (value,index) min
//    (value-min butterfly + exact-equality first-index — validated r13/r8-run).
//  - residual chain (x - q0) - q1 elementwise fp32, recomputed from codes per level.
//  - Srow: per-8-elem left-assoc square sums, then 16-chunk ascending sum.
//  - losses loose (~2%); __expf on probs-only path (validated r8-run).
//
// Round 15. r9's two clean negatives: (a) bank conflicts 7.9M->13K changed
// NOTHING (7.9M cycles chip-wide = 31K/CU = 1%); (b) scalar-pipe rows lose:
// resT round-trips HBM (FETCH 40->69MB) and mixed smem/ds forces lgkmcnt(0)
// serialization. The r7(910,VALUBusy 57,occ 46.5) vs r8/r9(963/970,37/31,~38)
// contrast says duration tracks RESIDENT WAVES: the per-kt stall (staging
// vmcnt + barrier convoy) is only absorbed by other blocks' waves; all rounds
// so far fit ~3 blocks/CU. This round sizes r7's skeleton for the 2048-thread
// cap: 512 thr (8 waves), 16 rows x 2 codes/thread (acc 32 -> VGPR ~56, no
// reg war), KT=2 -> Wtile[2][2048]=16KB, total LDS ~29KB -> 4 blocks/CU =
// 32 waves = 100%. Rows from x/W in-kernel (stage_level dropped). Cheap
// argmin + __expf kept (validated). Phase-0/fmaf/d numerics bit-identical.
// Checks: occ 70-100%, VALUBusy 65-85%, VGPR<=64, FETCH ~40MB, WRITE ~133MB,
// rvq 550-700/level. Pre-committed: occ>=75% but dur>=850 => platform ceiling,
// write the arithmetic and stop.

#define NROWS   131072
#define DIMS    128
#define KCODES  1024
#define NLEV    3

#define QF_OFF   ((size_t)NROWS * DIMS)          // 16777216
#define CODE_OFF QF_OFF
#define SCAL_OFF (QF_OFF + (size_t)NROWS * 3)    // 17170432

// ---------------- ws layout ----------------
// avgp   : 3*1024 floats  @ 0        (12288 B)
// commit : 3 doubles      @ 12288    (24 B)
// wk     : 3*1024 floats  @ 12320    (12288 B)
// WT     : 3*128*1024 fl  @ 24608    (1572864 B)  k-major codebooks WT[l][k][c]
#define WS_COMMIT_OFF 12288
#define WS_WK_OFF     12320
#define WS_WT_OFF     24608

__global__ __launch_bounds__(256) void init_acc(float* avgp, double* commit) {
    for (int i = threadIdx.x; i < 3072; i += 256) avgp[i] = 0.0f;
    if (threadIdx.x < 3) commit[threadIdx.x] = 0.0;
}

__global__ __launch_bounds__(256) void wnorm_kernel(const float* __restrict__ W,
                                                    float* __restrict__ wk) {
    const int wave = threadIdx.x >> 6, lane = threadIdx.x & 63;
    const int c = blockIdx.x * 4 + wave;          // 0..3071 (level*1024 + k)
    const float2 v = *(const float2*)(W + (size_t)c * DIMS + 2 * lane);
    float s = v.x * v.x + v.y * v.y;
#pragma unroll
    for (int m = 32; m >= 1; m >>= 1) s += __shfl_xor(s, m, 64);
    if (lane == 0) wk[c] = s;
}

// WT[l][k][c] = W[l][c][k]   (plain k-major)
__global__ __launch_bounds__(256) void transpose_w(const float* __restrict__ W,
                                                   float* __restrict__ WT) {
    __shared__ float tile[32][65];
    const int l = blockIdx.z, k0 = blockIdx.y * 32, c0 = blockIdx.x * 64;
    const float* Wl = W + (size_t)l * KCODES * DIMS;
    float* WTl = WT + (size_t)l * DIMS * KCODES;
    {
        const int ci = threadIdx.x >> 2;            // 0..63
        const int kg = (threadIdx.x & 3) * 8;       // 0,8,16,24
        const float4 a = *(const float4*)(Wl + (size_t)(c0 + ci) * DIMS + k0 + kg);
        const float4 b = *(const float4*)(Wl + (size_t)(c0 + ci) * DIMS + k0 + kg + 4);
        tile[kg + 0][ci] = a.x; tile[kg + 1][ci] = a.y;
        tile[kg + 2][ci] = a.z; tile[kg + 3][ci] = a.w;
        tile[kg + 4][ci] = b.x; tile[kg + 5][ci] = b.y;
        tile[kg + 6][ci] = b.z; tile[kg + 7][ci] = b.w;
    }
    __syncthreads();
    {
        const int k = threadIdx.x >> 3;             // 0..31
        const int cg = (threadIdx.x & 7) * 8;       // 0..56
        float4 o0, o1;
        o0.x = tile[k][cg + 0]; o0.y = tile[k][cg + 1];
        o0.z = tile[k][cg + 2]; o0.w = tile[k][cg + 3];
        o1.x = tile[k][cg + 4]; o1.y = tile[k][cg + 5];
        o1.z = tile[k][cg + 6]; o1.w = tile[k][cg + 7];
        *(float4*)(WTl + (size_t)(k0 + k) * KCODES + c0 + cg)     = o0;
        *(float4*)(WTl + (size_t)(k0 + k) * KCODES + c0 + cg + 4) = o1;
    }
}

__global__ __launch_bounds__(512) void rvq_level(
    const float* __restrict__ x, const float* __restrict__ W,
    const float* __restrict__ WT, const float* __restrict__ wk,
    float* __restrict__ out, float* __restrict__ avgp,
    double* __restrict__ commit, const int level) {

    __shared__ float Wtile[2][2048];   // double-buffered W tile: 2 k-rows x 1024
    __shared__ float rowT[128][20];    // residual rows, k-major (80B rows: 16B-aligned)
    __shared__ float redf[16][17];
    __shared__ float Srow[16];
    __shared__ float wminv[16][8];     // per-wave argmin partials (8 waves)
    __shared__ int   wmini[16][8];
    __shared__ float rowmin[16];
    __shared__ float wsum[16][8];
    __shared__ float rcpL[16];

    const int t = threadIdx.x;
    const int wave = t >> 6, lane = t & 63;
    const int c = wave * 128 + lane * 2;          // this thread's 2 codes
    const size_t base = (size_t)blockIdx.x * 16;
    const float* codesF = out + CODE_OFF;
    const float* WTl = WT + (size_t)level * DIMS * KCODES;
    const float* wkl = wk + level * KCODES;

    // ---- phase 0 (t<256): stage 16 residual rows (k-major), bit-exact chain ----
    if (t < 256) {
        const int r = t >> 4, i = t & 15;
        const size_t n = base + r;
        float4 v0 = *(const float4*)(x + n * DIMS + i * 8);
        float4 v1 = *(const float4*)(x + n * DIMS + i * 8 + 4);
        for (int j = 0; j < level; ++j) {
            const int idx = (int)codesF[n * 3 + j];
            const float* q = W + ((size_t)(j * KCODES + idx)) * DIMS + i * 8;
            const float4 q0 = *(const float4*)q;
            const float4 q1 = *(const float4*)(q + 4);
            v0.x = __fsub_rn(v0.x, q0.x); v0.y = __fsub_rn(v0.y, q0.y);
            v0.z = __fsub_rn(v0.z, q0.z); v0.w = __fsub_rn(v0.w, q0.w);
            v1.x = __fsub_rn(v1.x, q1.x); v1.y = __fsub_rn(v1.y, q1.y);
            v1.z = __fsub_rn(v1.z, q1.z); v1.w = __fsub_rn(v1.w, q1.w);
        }
        rowT[i * 8 + 0][r] = v0.x; rowT[i * 8 + 1][r] = v0.y;
        rowT[i * 8 + 2][r] = v0.z; rowT[i * 8 + 3][r] = v0.w;
        rowT[i * 8 + 4][r] = v1.x; rowT[i * 8 + 5][r] = v1.y;
        rowT[i * 8 + 6][r] = v1.z; rowT[i * 8 + 7][r] = v1.w;
        float sq = v0.x * v0.x + v0.y * v0.y + v0.z * v0.z + v0.w * v0.w
                 + v1.x * v1.x + v1.y * v1.y + v1.z * v1.z + v1.w * v1.w;
        redf[r][i] = sq;
    }
    __syncthreads();
    if (t < 16) {
        float s = 0.f;
        for (int i = 0; i < 16; ++i) s += redf[t][i];
        Srow[t] = s;   // on-grid shift: order can't affect argmin/softmax
    }

    // ---- phase 1: tiled GEMM. acc[r] = row_r · W_{c,c+1}, k ascending. ----
    float2 acc[16];
#pragma unroll
    for (int r = 0; r < 16; ++r) { acc[r].x = 0.f; acc[r].y = 0.f; }

    // prologue: stage tile 0 (k-rows 0,1) into buf 0 (512 thr x 16B = 8KB)
    *(float4*)&Wtile[0][t * 4] = *(const float4*)(WTl + t * 4);
    __syncthreads();   // covers Srow + rowT + tile 0

    int buf = 0;
#pragma unroll 1
    for (int kt = 0; kt < 64; ++kt) {
        // issue-early: global load for tile kt+1 (clamped; dead on last iter)
        const float* Wn = WTl + (size_t)((kt + 1 < 64) ? (kt + 1) : 0) * 2048;
        const float4 g = *(const float4*)(Wn + t * 4);

        // consume current tile: 2 k-steps x 16 rows x 2 codes = 64 FMA
        const float* Wt = &Wtile[buf][0];
        {   // k = 2*kt
            const float2 wv = *(const float2*)&Wt[c];
#pragma unroll
            for (int rr = 0; rr < 4; ++rr) {
                const float4 rv = *(const float4*)&rowT[2 * kt][rr * 4];   // broadcast
                acc[rr * 4 + 0].x = fmaf(rv.x, wv.x, acc[rr * 4 + 0].x);
                acc[rr * 4 + 0].y = fmaf(rv.x, wv.y, acc[rr * 4 + 0].y);
                acc[rr * 4 + 1].x = fmaf(rv.y, wv.x, acc[rr * 4 + 1].x);
                acc[rr * 4 + 1].y = fmaf(rv.y, wv.y, acc[rr * 4 + 1].y);
                acc[rr * 4 + 2].x = fmaf(rv.z, wv.x, acc[rr * 4 + 2].x);
                acc[rr * 4 + 2].y = fmaf(rv.z, wv.y, acc[rr * 4 + 2].y);
                acc[rr * 4 + 3].x = fmaf(rv.w, wv.x, acc[rr * 4 + 3].x);
                acc[rr * 4 + 3].y = fmaf(rv.w, wv.y, acc[rr * 4 + 3].y);
            }
        }
        {   // k = 2*kt+1
            const float2 wv = *(const float2*)&Wt[1024 + c];
#pragma unroll
            for (int rr = 0; rr < 4; ++rr) {
                const float4 rv = *(const float4*)&rowT[2 * kt + 1][rr * 4];
                acc[rr * 4 + 0].x = fmaf(rv.x, wv.x, acc[rr * 4 + 0].x);
                acc[rr * 4 + 0].y = fmaf(rv.x, wv.y, acc[rr * 4 + 0].y);
                acc[rr * 4 + 1].x = fmaf(rv.y, wv.x, acc[rr * 4 + 1].x);
                acc[rr * 4 + 1].y = fmaf(rv.y, wv.y, acc[rr * 4 + 1].y);
                acc[rr * 4 + 2].x = fmaf(rv.z, wv.x, acc[rr * 4 + 2].x);
                acc[rr * 4 + 2].y = fmaf(rv.z, wv.y, acc[rr * 4 + 2].y);
                acc[rr * 4 + 3].x = fmaf(rv.w, wv.x, acc[rr * 4 + 3].x);
                acc[rr * 4 + 3].y = fmaf(rv.w, wv.y, acc[rr * 4 + 3].y);
            }
        }

        // write-late: vmcnt wait lands here, after the FMA block (T14)
        *(float4*)&Wtile[buf ^ 1][t * 4] = g;
        __syncthreads();
        buf ^= 1;
    }

    // ---- phase 2: d in place; per-row argmin (value butterfly + equality
    // first-index, bit-identical to lexicographic — validated). ----
    const float2 wkv = *(const float2*)(wkl + c);
#pragma unroll
    for (int r = 0; r < 16; ++r) {
        const float Sr = Srow[r];
        float dx = __fadd_rn(__fsub_rn(Sr, __fmul_rn(2.0f, acc[r].x)), wkv.x);
        float dy = __fadd_rn(__fsub_rn(Sr, __fmul_rn(2.0f, acc[r].y)), wkv.y);
        acc[r].x = dx; acc[r].y = dy;
        float v = fminf(dx, dy);
#pragma unroll
        for (int m = 1; m < 64; m <<= 1) v = fminf(v, __shfl_xor(v, m, 64));
        int bi = 0x7FFFFFFF;                       // first index with d == vmin
        if (dy == v) bi = c + 1;
        if (dx == v) bi = c;
#pragma unroll
        for (int m = 1; m < 64; m <<= 1) bi = min(bi, __shfl_xor(bi, m, 64));
        if (lane == 0) { wminv[r][wave] = v; wmini[r][wave] = bi; }
    }
    __syncthreads();
    if (t < 16) {
        float v = wminv[t][0];
        for (int w = 1; w < 8; ++w) v = fminf(v, wminv[t][w]);
        int bi = 0x7FFFFFFF;
        for (int w = 7; w >= 0; --w)
            if (wminv[t][w] == v) bi = (wmini[t][w] < bi) ? wmini[t][w] : bi;
        rowmin[t] = v;
        out[CODE_OFF + (base + t) * 3 + level] = (float)bi;
    }
    __syncthreads();

    // ---- phase 3: e = exp(dmin - d) in place (__expf: probs-only path),
    // row sums via shuffle ----
#pragma unroll
    for (int r = 0; r < 16; ++r) {
        const float mn = rowmin[r];
        const float ex = __expf(__fsub_rn(mn, acc[r].x));
        const float ey = __expf(__fsub_rn(mn, acc[r].y));
        acc[r].x = ex; acc[r].y = ey;
        float s = ex + ey;
#pragma unroll
        for (int m = 1; m < 64; m <<= 1) s += __shfl_xor(s, m, 64);
        if (lane == 0) wsum[r][wave] = s;
    }
    __syncthreads();
    if (t < 16) {
        float L = 0.f;
        for (int w = 0; w < 8; ++w) L += wsum[t][w];
        rcpL[t] = 1.0f / L;
    }
    if (t == 64) {   // commit partial: d at argmin == ||r - q||^2 (loss tolerance loose)
        double cs = 0.0;
        for (int r = 0; r < 16; ++r) cs += (double)rowmin[r];
        atomicAdd(&commit[level], cs);
    }
    __syncthreads();

    // ---- phase 4: avg_probs partials (fp32 atomics, one per code per block) ----
    {
        float s0 = 0.f, s1 = 0.f;
#pragma unroll
        for (int r = 0; r < 16; ++r) {
            const float rl = rcpL[r];
            s0 = fmaf(acc[r].x, rl, s0);
            s1 = fmaf(acc[r].y, rl, s1);
        }
        atomicAdd(&avgp[level * KCODES + c + 0], s0);
        atomicAdd(&avgp[level * KCODES + c + 1], s1);
    }
}

__global__ __launch_bounds__(256) void finalize_kernel(const float* __restrict__ avgp,
                                                       const double* __restrict__ commit,
                                                       float* __restrict__ out) {
    __shared__ double red[256];
    __shared__ float  kls[3];
    const int t = threadIdx.x;
    for (int l = 0; l < 3; ++l) {
        double p = 0.0;
        for (int k = t; k < KCODES; k += 256) {
            const float avg = avgp[l * KCODES + k] * (1.0f / 131072.0f);
            p += (double)avg * log((double)avg * 1024.0 + 1e-8);
        }
        red[t] = p; __syncthreads();
        for (int off = 128; off >= 1; off >>= 1) {
            if (t < off) red[t] += red[t + off];
            __syncthreads();
        }
        if (t == 0) kls[l] = (float)red[0];
        __syncthreads();
    }
    if (t == 0) {
        float cv = 0.f, u = 0.f;
        for (int l = 0; l < 3; ++l) {
            const float m = (float)(commit[l] * (1.0 / 16777216.0));
            cv = __fadd_rn(cv, m);                      // + mean((sg(r)-q)^2)
            cv = __fadd_rn(cv, __fmul_rn(0.25f, m));    // + BETA * mean((r-sg(q))^2)
            u = __fadd_rn(u, __fmul_rn(1e-3f, kls[l]));
        }
        out[SCAL_OFF]     = cv;
        out[SCAL_OFF + 1] = u;
    }
}

__global__ __launch_bounds__(256) void gather_kernel(const float* __restrict__ W,
                                                     float* __restrict__ out) {
    const size_t g = (size_t)blockIdx.x * 256 + threadIdx.x;   // f4 index
    const size_t n = g >> 5;
    const int f = (int)(g & 31);
    const float* codes = out + CODE_OFF + n * 3;
    const int c0 = (int)codes[0], c1 = (int)codes[1], c2 = (int)codes[2];
    const float4 a = *(const float4*)(W + (size_t)c0 * DIMS + 4 * f);
    const float4 b = *(const float4*)(W + (size_t)(KCODES + c1) * DIMS + 4 * f);
    const float4 c = *(const float4*)(W + (size_t)(2 * KCODES + c2) * DIMS + 4 * f);
    float4 o;   // ((q1 + q2) + q3), fp32 like reference
    o.x = __fadd_rn(__fadd_rn(a.x, b.x), c.x);
    o.y = __fadd_rn(__fadd_rn(a.y, b.y), c.y);
    o.z = __fadd_rn(__fadd_rn(a.z, b.z), c.z);
    o.w = __fadd_rn(__fadd_rn(a.w, b.w), c.w);
    *(float4*)(out + n * DIMS + 4 * f) = o;
}

extern "C" void kernel_launch(void* const* d_in, const int* in_sizes, int n_in,
                              void* d_out, int out_size, void* d_ws, size_t ws_size,
                              hipStream_t stream) {
    const float* x = (const float*)d_in[0];
    const float* W = (const float*)d_in[1];
    float* out = (float*)d_out;
    float*  avgp   = (float*)d_ws;
    double* commit = (double*)((char*)d_ws + WS_COMMIT_OFF);
    float*  wkp    = (float*)((char*)d_ws + WS_WK_OFF);
    float*  WT     = (float*)((char*)d_ws + WS_WT_OFF);

    hipLaunchKernelGGL(init_acc, dim3(1), dim3(256), 0, stream, avgp, commit);
    hipLaunchKernelGGL(wnorm_kernel, dim3(768), dim3(256), 0, stream, W, wkp);
    hipLaunchKernelGGL(transpose_w, dim3(16, 4, 3), dim3(256), 0, stream, W, WT);
    for (int l = 0; l < NLEV; ++l)
        hipLaunchKernelGGL(rvq_level, dim3(NROWS / 16), dim3(512), 0, stream,
                           x, W, WT, wkp, out, avgp, commit, l);
    hipLaunchKernelGGL(finalize_kernel, dim3(1), dim3(256), 0, stream, avgp, commit, out);
    hipLaunchKernelGGL(gather_kernel, dim3((NROWS * 32) / 256), dim3(256), 0, stream, W, out);
}